// Round 2
// baseline (589.139 us; speedup 1.0000x reference)
//
#include <hip/hip_runtime.h>

// ---------------- problem constants ----------------
#define M_DIM 2048        // tlen*batch
#define K_DIM 1024        // input_size
#define N_DIM 32000       // vocab
#define CVOCAB 120
#define AGENDA 100
#define SLEN 400
#define CTX 300
#define BATCH 16
#define OUT_STRIDE 32120  // vocab + cvocab
#define PAD_IDX 1

#define TM 256            // GEMM tile M
#define TN 256            // GEMM tile N
#define BK 64             // GEMM K-step (two k-halves of 32)
#define NKT (K_DIM / BK)  // 16
#define MT (M_DIM / TM)   // 8
#define NT (N_DIM / TN)   // 125

typedef float f32x4_t  __attribute__((ext_vector_type(4)));
typedef __bf16 bf16x8_t __attribute__((ext_vector_type(8)));
typedef unsigned short u16x8_t __attribute__((ext_vector_type(8)));
typedef unsigned short u16x4_t __attribute__((ext_vector_type(4)));

// RNE fp32 -> bf16 (values are all normal, no NaN handling needed)
__device__ __forceinline__ unsigned short f2bf(float f) {
    union { float f; unsigned int u; } c; c.f = f;
    unsigned int u = c.u;
    u += 0x7FFFu + ((u >> 16) & 1u);
    return (unsigned short)(u >> 16);
}

// fp32 <-> fp16 (exp values in [0, ~60]: fp16-safe, 2^-11 rel err << tolerance)
__device__ __forceinline__ unsigned short f2h(float f) {
    _Float16 h = (_Float16)f;
    unsigned short u; __builtin_memcpy(&u, &h, 2); return u;
}
__device__ __forceinline__ float h2f(unsigned short u) {
    _Float16 h; __builtin_memcpy(&h, &u, 2); return (float)h;
}

// async 16B global->LDS (dest = wave-uniform base + lane*16)
__device__ __forceinline__ void async_copy16(const void* gsrc, void* ldst) {
    __builtin_amdgcn_global_load_lds(
        (__attribute__((address_space(1))) unsigned int*)(gsrc),
        (__attribute__((address_space(3))) unsigned int*)(ldst),
        16, 0, 0);
}

// ---------------- kernel 1: fp32 -> bf16 cast of W and hidden ----------------
__global__ void cast_bf16_kernel(const float4* __restrict__ W, const float4* __restrict__ H,
                                 unsigned short* __restrict__ Wb, unsigned short* __restrict__ Hb) {
    const size_t NW4 = (size_t)N_DIM * K_DIM / 4;   // 8,192,000
    const size_t NH4 = (size_t)M_DIM * K_DIM / 4;   // 524,288
    size_t idx = (size_t)blockIdx.x * 256 + threadIdx.x;
    float4 v; unsigned short* dst;
    if (idx < NW4)            { v = W[idx];        dst = Wb + idx * 4; }
    else if (idx < NW4 + NH4) { v = H[idx - NW4];  dst = Hb + (idx - NW4) * 4; }
    else return;
    u16x4_t o;
    o[0] = f2bf(v.x); o[1] = f2bf(v.y); o[2] = f2bf(v.z); o[3] = f2bf(v.w);
    *(u16x4_t*)dst = o;
}

// ---------------- kernel 2: p_copy = sigmoid(hidden @ W_copy^T + b_copy) ----------------
// Also zeroes rowsum (runs before GEMM) so the memset dispatch goes away.
__global__ void pcopy_kernel(const float* __restrict__ hidden, const float* __restrict__ Wc,
                             const float* __restrict__ bc, float* __restrict__ pcopy,
                             float* __restrict__ rowsum) {
    int row  = blockIdx.x * 4 + (threadIdx.x >> 6);  // 4 waves/block, 1 row/wave
    int lane = threadIdx.x & 63;
    const float4* h = (const float4*)(hidden + (size_t)row * K_DIM);
    const float4* w = (const float4*)Wc;
    float s = 0.f;
    #pragma unroll
    for (int i = 0; i < 4; ++i) {
        float4 a = h[lane + 64 * i];
        float4 b = w[lane + 64 * i];
        s += a.x * b.x + a.y * b.y + a.z * b.z + a.w * b.w;
    }
    #pragma unroll
    for (int m = 1; m < 64; m <<= 1) s += __shfl_xor(s, m);
    if (lane == 0) {
        float p = 1.0f / (1.0f + __expf(-(s + bc[0])));
        pcopy[row] = p;
        rowsum[row] = 0.0f;
    }
}

// ---------------- kernel 3: GEMM + exp + row-sum --------------------------------
// 256x256 tile, 8 waves (wave tile 128x64), 8-phase schedule with counted vmcnt
// (T3+T4) and setprio around MFMA clusters (T5).
//
// LDS layout (128 KB): A slots [parity][khalf] of 256 rows x 32 k (16 KB each),
// then B slots. Slot chunk c (16B) of row m holds source k-group j = c ^ swz(m),
// swz(m) = (m>>1)&3  -> uniform 2-way bank aliasing on ds_read_b128 (free).
//
// Per tile t (parity p): 4 phases (mh,s) = (0,0),(1,0),(0,1),(1,1); each phase:
// 4-8 ds_read_b128 + one 16KB half-stage + barrier + 16 MFMA + barrier.
// Stage schedule: ph1: A[p^1][1] <- tile t+1 kh1 (slot freed end of t-1 ph4)
//                 ph2: B[p^1][1] <- tile t+1 kh1
//                 ph3: A[p ][0] <- tile t+2 kh0 (slot freed end of t ph2)
//                 ph4: B[p ][0] <- tile t+2 kh0
// Tile-top wait: vmcnt(4) (allow the 2 newest half-stages = tile t+1 kh0 pair
// to remain in flight); vmcnt(0) only at the last tile. Never drained mid-loop.
__global__ __launch_bounds__(512, 2) void gemm_exp_kernel(
    const unsigned short* __restrict__ A,   // M x K bf16
    const unsigned short* __restrict__ B,   // N x K bf16
    const float* __restrict__ bias,         // N
    float* __restrict__ out,                // row stride OUT_STRIDE (fp16 staging area)
    float* __restrict__ rowsum)             // M (zeroed by pcopy_kernel)
{
    __shared__ unsigned short lds[65536];   // 128 KB: A [0,32768) us, B [32768,65536) us
    __shared__ float sRow[TM];              // 1 KB

    const int tid  = threadIdx.x;           // 0..511
    const int lane = tid & 63;
    const int q    = lane >> 4;             // k-chunk select (0..3)
    const int lr   = lane & 15;             // row-within-fragment
    const int wv   = tid >> 6;              // 0..7
    const int wr   = wv >> 2;               // 0..1 -> 128-row half
    const int wc   = wv & 3;                // 0..3 -> 64-col quarter

    // XCD swizzle: each XCD walks its 125 tiles M-fastest (B-panel L2 reuse)
    const int bid = blockIdx.x;
    const int t0  = (bid & 7) * NT + (bid >> 3);   // 1000 = 8*125: bijective
    const int rowBase = (t0 & 7) * TM;
    const int colBase = (t0 >> 3) * TN;

    if (tid < TM) sRow[tid] = 0.0f;

    // ---- stage source addresses (pre-swizzled global; dest is linear) ----
    // pidx = tid + i*512: row m = pidx>>2, chunk c = pidx&3, src k-group j = c^swz(m)
    const int mS0 = tid >> 2,         cS0 = tid & 3;
    const int mS1 = (tid + 512) >> 2, cS1 = tid & 3;
    const int jS0 = cS0 ^ ((mS0 >> 1) & 3);
    const int jS1 = cS1 ^ ((mS1 >> 1) & 3);
    const unsigned short* aS0 = A + (size_t)(rowBase + mS0) * K_DIM + jS0 * 8;
    const unsigned short* aS1 = A + (size_t)(rowBase + mS1) * K_DIM + jS1 * 8;
    const unsigned short* bS0 = B + (size_t)(colBase + mS0) * K_DIM + jS0 * 8;
    const unsigned short* bS1 = B + (size_t)(colBase + mS1) * K_DIM + jS1 * 8;
    const int dus0 = wv * 512;              // LDS dest (us) within slot, i=0
    const int dus1 = 4096 + wv * 512;       // i=1  (HW adds lane*16 B)

    // ---- fragment LDS offsets (us within slot: row m -> m*32 + chunk*8) ----
    int aoff[8], boff[4];
    #pragma unroll
    for (int f = 0; f < 8; ++f) {
        int m = wr * 128 + f * 16 + lr;
        aoff[f] = m * 32 + ((q ^ ((m >> 1) & 3)) * 8);
    }
    #pragma unroll
    for (int c = 0; c < 4; ++c) {
        int n = wc * 64 + c * 16 + lr;
        boff[c] = n * 32 + ((q ^ ((n >> 1) & 3)) * 8);
    }

    f32x4_t acc[8][4] = {};

#define STAGE_A(TT, S) do {                                                  \
    unsigned short* d_ = lds + (((TT) & 1) * 2 + (S)) * 8192;                \
    const size_t ko_ = (size_t)(TT) * 64 + (S) * 32;                         \
    async_copy16(aS0 + ko_, d_ + dus0);                                      \
    async_copy16(aS1 + ko_, d_ + dus1); } while (0)

#define STAGE_B(TT, S) do {                                                  \
    unsigned short* d_ = lds + 32768 + (((TT) & 1) * 2 + (S)) * 8192;        \
    const size_t ko_ = (size_t)(TT) * 64 + (S) * 32;                         \
    async_copy16(bS0 + ko_, d_ + dus0);                                      \
    async_copy16(bS1 + ko_, d_ + dus1); } while (0)

    // prologue: tile0 (all 4 halves) + tile1 kh0  -> 6 groups = 12 loads/wave
    STAGE_A(0, 0); STAGE_B(0, 0);
    STAGE_A(0, 1); STAGE_B(0, 1);
    STAGE_A(1, 0); STAGE_B(1, 0);

    #pragma unroll 1
    for (int t = 0; t < NKT; ++t) {
        const int p = t & 1;
        // tile-top wait: oldest 4 groups (this tile's 4 halves) must have landed
        if (t < NKT - 1) asm volatile("s_waitcnt vmcnt(4)" ::: "memory");
        else             asm volatile("s_waitcnt vmcnt(0)" ::: "memory");
        __builtin_amdgcn_s_barrier();
        __builtin_amdgcn_sched_barrier(0);

        u16x8_t bfv[4];   // B fragments persist across the mh=0 -> mh=1 phases

#define PHASE(MH, S, STAGE_STMT) do {                                        \
        const int sa_ = (p * 2 + (S)) * 8192;                                \
        const int sb_ = 32768 + sa_;                                         \
        u16x8_t af_[4];                                                      \
        _Pragma("unroll")                                                    \
        for (int r = 0; r < 4; ++r)                                          \
            af_[r] = *(const u16x8_t*)(lds + sa_ + aoff[(MH) * 4 + r]);      \
        if ((MH) == 0) {                                                     \
            _Pragma("unroll")                                                \
            for (int c = 0; c < 4; ++c)                                      \
                bfv[c] = *(const u16x8_t*)(lds + sb_ + boff[c]);             \
        }                                                                    \
        STAGE_STMT;                                                          \
        __builtin_amdgcn_sched_barrier(0);                                   \
        __builtin_amdgcn_s_barrier();                                        \
        __builtin_amdgcn_s_setprio(1);                                       \
        _Pragma("unroll")                                                    \
        for (int r = 0; r < 4; ++r) {                                        \
            _Pragma("unroll")                                                \
            for (int c = 0; c < 4; ++c)                                      \
                acc[(MH) * 4 + r][c] = __builtin_amdgcn_mfma_f32_16x16x32_bf16( \
                    __builtin_bit_cast(bf16x8_t, af_[r]),                    \
                    __builtin_bit_cast(bf16x8_t, bfv[c]),                    \
                    acc[(MH) * 4 + r][c], 0, 0, 0);                          \
        }                                                                    \
        __builtin_amdgcn_s_setprio(0);                                       \
        __builtin_amdgcn_sched_barrier(0);                                   \
        __builtin_amdgcn_s_barrier(); } while (0)

        PHASE(0, 0, { if (t < NKT - 1) STAGE_A(t + 1, 1); });
        PHASE(1, 0, { if (t < NKT - 1) STAGE_B(t + 1, 1); });
        PHASE(0, 1, { if (t < NKT - 2) STAGE_A(t + 2, 0); });
        PHASE(1, 1, { if (t < NKT - 2) STAGE_B(t + 2, 0); });
#undef PHASE
    }
#undef STAGE_A
#undef STAGE_B

    // epilogue: C/D layout col=lane&15 (vocab n), row=quad*4+reg (token m)
    float bb[4];
    #pragma unroll
    for (int c = 0; c < 4; ++c) bb[c] = bias[colBase + wc * 64 + c * 16 + lr];

    #pragma unroll
    for (int f = 0; f < 8; ++f) {
        float rsum[4] = {0.f, 0.f, 0.f, 0.f};
        #pragma unroll
        for (int c = 0; c < 4; ++c) {
            int gcol = colBase + wc * 64 + c * 16 + lr;
            bool pad = (gcol == PAD_IDX);
            #pragma unroll
            for (int d = 0; d < 4; ++d) {
                int grow = rowBase + wr * 128 + f * 16 + q * 4 + d;
                float e = pad ? 0.0f : __expf(acc[f][c][d] + bb[c]);
                // fp16 in-place: first 64000 B of the row's fp32 region
                ((unsigned short*)(out + (size_t)grow * OUT_STRIDE))[gcol] = f2h(e);
                rsum[d] += e;
            }
        }
        #pragma unroll
        for (int d = 0; d < 4; ++d) {
            float v = rsum[d];
            v += __shfl_xor(v, 1);
            v += __shfl_xor(v, 2);
            v += __shfl_xor(v, 4);
            v += __shfl_xor(v, 8);
            if (lr == 0) {
                int lrow = wr * 128 + f * 16 + q * 4 + d;
                atomicAdd(&sRow[lrow], v);   // LDS atomic: fewer global atomics
            }
        }
    }
    __syncthreads();
    if (tid < TM) atomicAdd(&rowsum[rowBase + tid], sRow[tid]);
}

// ---------------- kernel 4: fused normalize + copy_prob + p_copy tail ----------------
// Reads the row's fp16 exp values (64 KB) into LDS, then expands to normalized
// fp32 in place. Halves the finalize read traffic and GEMM's write traffic.
__global__ __launch_bounds__(512) void finalize_kernel(
    float* __restrict__ out, const float* __restrict__ rowsum,
    const float* __restrict__ pcopy, const float* __restrict__ attn,
    const float* __restrict__ src_map, float* __restrict__ out_tail) {
    const int n   = blockIdx.x;        // row (t*BATCH + b)
    const int tid = threadIdx.x;       // 512 threads
    __shared__ unsigned short sE[N_DIM];   // 64000 B
    __shared__ float ma[AGENDA];

    const float p = pcopy[n];
    const float scale = (1.0f - p) / rowsum[n];

    // stage fp16 row into LDS before any fp32 write clobbers it
    const u16x8_t* src = (const u16x8_t*)(out + (size_t)n * OUT_STRIDE);
    for (int j = tid; j < N_DIM / 8; j += 512)
        *(u16x8_t*)(sE + j * 8) = src[j];
    if (tid < AGENDA) ma[tid] = attn[(size_t)n * SLEN + CTX + tid] * p;
    __syncthreads();

    float4* row4 = (float4*)(out + (size_t)n * OUT_STRIDE);
    for (int j = tid; j < N_DIM / 4; j += 512) {
        u16x4_t h = *(const u16x4_t*)(sE + j * 4);
        float4 v;
        v.x = h2f(h[0]) * scale;
        v.y = h2f(h[1]) * scale;
        v.z = h2f(h[2]) * scale;
        v.w = h2f(h[3]) * scale;
        row4[j] = v;
    }

    if (tid < CVOCAB) {
        int bidx = n & (BATCH - 1);
        float s = 0.f;
        #pragma unroll 4
        for (int a = 0; a < AGENDA; ++a)
            s += ma[a] * src_map[(size_t)(a * BATCH + bidx) * CVOCAB + tid];
        out[(size_t)n * OUT_STRIDE + N_DIM + tid] = s;
    }
    if (tid == 0) out_tail[n] = p;
}

// ---------------- launch ----------------
extern "C" void kernel_launch(void* const* d_in, const int* in_sizes, int n_in,
                              void* d_out, int out_size, void* d_ws, size_t ws_size,
                              hipStream_t stream) {
    const float* hidden  = (const float*)d_in[0];
    const float* attn    = (const float*)d_in[1];
    const float* src_map = (const float*)d_in[2];
    const float* W       = (const float*)d_in[3];
    const float* b       = (const float*)d_in[4];
    const float* W_copy  = (const float*)d_in[5];
    const float* b_copy  = (const float*)d_in[6];
    float* out = (float*)d_out;

    // workspace layout (unchanged, ~70 MB)
    char* ws = (char*)d_ws;
    unsigned short* Wb = (unsigned short*)ws;                               // 65,536,000 B
    unsigned short* Hb = (unsigned short*)(ws + 65536000);                  //  4,194,304 B
    float* rowsum      = (float*)(ws + 65536000 + 4194304);                 //      8,192 B
    float* pcopy       = (float*)(ws + 65536000 + 4194304 + 8192);          //      8,192 B

    float* out_tail = out + (size_t)M_DIM * OUT_STRIDE;  // p_copy output

    // 1. cast W + hidden to bf16
    {
        size_t total4 = (size_t)N_DIM * K_DIM / 4 + (size_t)M_DIM * K_DIM / 4;
        int blocks = (int)((total4 + 255) / 256);
        cast_bf16_kernel<<<blocks, 256, 0, stream>>>((const float4*)W, (const float4*)hidden, Wb, Hb);
    }
    // 2. p_copy (also zeroes rowsum — ws is poisoned every call)
    pcopy_kernel<<<M_DIM / 4, 256, 0, stream>>>(hidden, W_copy, b_copy, pcopy, rowsum);
    // 3. GEMM + exp + rowsum  (8-phase schedule, 512 threads, XCD-swizzled)
    gemm_exp_kernel<<<MT * NT, 512, 0, stream>>>(Hb, Wb, b, out, rowsum);
    // 4. fused normalize + copy_prob + p_copy tail
    finalize_kernel<<<M_DIM, 512, 0, stream>>>(out, rowsum, pcopy, attn, src_map, out_tail);
}